// Round 1
// baseline (439.536 us; speedup 1.0000x reference)
//
#include <hip/hip_runtime.h>
#include <math.h>

#define NRAYS 65536
#define T0N 128
#define T1N 64
#define CN 16
#define RPB 4                   // rays (waves) per block
#define NBLK (NRAYS / RPB)      // 16384

#define IMG_OFF   0
#define DEPTH_OFF (NRAYS * 3)
#define FXYZ_OFF  (NRAYS * 4)
#define PROP_OFF  (NRAYS * 7)
#define DIST_OFF  (NRAYS * 7 + 1)

__device__ __forceinline__ float wave_sum(float x) {
#pragma unroll
  for (int off = 1; off < 64; off <<= 1) x += __shfl_xor(x, off, 64);
  return x;  // all lanes hold the total
}

__device__ __forceinline__ float scan_incl(float x, int lane) {
#pragma unroll
  for (int off = 1; off < 64; off <<= 1) {
    float y = __shfl_up(x, off, 64);
    if (lane >= off) x += y;
  }
  return x;  // inclusive prefix sum across 64 lanes
}

__device__ __forceinline__ float spacing_fn(float x) {
  return (x < 1.0f) ? (x * 0.5f) : (1.0f - 1.0f / (2.0f * x));
}
__device__ __forceinline__ float spacing_inv_fn(float x) {
  return (x < 0.5f) ? (2.0f * x) : (1.0f / (2.0f - 2.0f * x));
}

// searchsorted side='right': count of a[m] <= v  (first index where a[m] > v)
__device__ __forceinline__ int ss_right(const float* a, int n, float v) {
  int lo = 0, hi = n;
  while (lo < hi) {
    int m = (lo + hi) >> 1;
    if (a[m] <= v) lo = m + 1; else hi = m;
  }
  return lo;
}

__global__ void __launch_bounds__(256) nerf_main(
    const float* __restrict__ rays_o, const float* __restrict__ rays_d,
    const float* __restrict__ aabb, const float* __restrict__ sig_c,
    const float* __restrict__ sig_f, const float* __restrict__ colors,
    const float* __restrict__ w_view, const float* __restrict__ b_view,
    float* __restrict__ out, float* __restrict__ ws_partials, int use_atomic) {
  __shared__ float s_cdf[RPB][129 + 1];
  __shared__ float s_bins1[RPB][66];
  __shared__ float s_rb1[RPB][66];
  __shared__ float s_w1[RPB][64];
  __shared__ float s_cw1[RPB][66];
  __shared__ float s_fimg[RPB][16];
  __shared__ float s_scal[RPB][2];

  const int wv = threadIdx.x >> 6;
  const int lane = threadIdx.x & 63;
  const int ray = blockIdx.x * RPB + wv;

  // ---- ray setup: near/far from aabb (all lanes redundantly; broadcast loads)
  float ro[3], rd[3];
#pragma unroll
  for (int c = 0; c < 3; ++c) { ro[c] = rays_o[ray * 3 + c]; rd[c] = rays_d[ray * 3 + c]; }
  float near = -3.0e38f, far = 3.0e38f;
#pragma unroll
  for (int c = 0; c < 3; ++c) {
    float dd = rd[c] + 1e-15f;
    float ta = (aabb[c] - ro[c]) / dd;
    float tb = (aabb[c + 3] - ro[c]) / dd;
    near = fmaxf(near, fminf(ta, tb));
    far = fminf(far, fmaxf(ta, tb));
  }
  if (far < near) { near = 1e9f; far = 1e9f; }
  near = fmaxf(near, 0.05f);
  const float s_near = spacing_fn(near), s_far = spacing_fn(far);

  // ---- coarse level: lane owns bins0 samples 2l, 2l+1
  const int i0 = 2 * lane, i1 = 2 * lane + 1;
  const float b_a = (float)i0 * (1.0f / 128.0f);
  const float b_b = (float)i1 * (1.0f / 128.0f);
  const float b_c = (float)(i1 + 1) * (1.0f / 128.0f);
  const float rb_a = spacing_inv_fn(s_near * (1.0f - b_a) + s_far * b_a);
  const float rb_b = spacing_inv_fn(s_near * (1.0f - b_b) + s_far * b_b);
  const float rb_c = spacing_inv_fn(s_near * (1.0f - b_c) + s_far * b_c);
  const float2 sg = ((const float2*)sig_c)[ray * 64 + lane];
  const float ds0 = (rb_b - rb_a) * sg.x;
  const float ds1 = (rb_c - rb_b) * sg.y;
  {  // exclusive cumsum of ds via pair-sum scan
  }
  float pr = ds0 + ds1;
  float Spr = scan_incl(pr, lane);
  float E0 = Spr - pr;  // sum of ds[0..2l-1]
  float w00 = (1.0f - expf(-ds0)) * expf(-E0);
  float w01 = (1.0f - expf(-ds1)) * expf(-(E0 + ds0));
  if (w00 != w00) w00 = 0.0f;  // nan_to_num
  if (w01 != w01) w01 = 0.0f;

  // ---- pdf/cdf for sample_pdf
  const float wp0 = w00 + 0.01f, wp1 = w01 + 0.01f;
  const float tot = wave_sum(wp0 + wp1);
  const float pdf0 = wp0 / tot, pdf1 = wp1 / tot;
  float prp = pdf0 + pdf1;
  float Sp = scan_incl(prp, lane);
  float Ep = Sp - prp;
  s_cdf[wv][i0 + 1] = fminf(Ep + pdf0, 1.0f);
  s_cdf[wv][i1 + 1] = fminf(Sp, 1.0f);
  if (lane == 0) s_cdf[wv][0] = 0.0f;
  __syncthreads();

  // ---- inverse-CDF sampling of 65 new bins (lane j; lane 63 also does j=64)
  auto sample_one = [&](int j) {
    const float u = ((float)j + 0.5f) * (1.0f / 65.0f);
    int inds = ss_right(&s_cdf[wv][0], 129, u);
    int below = max(min(inds - 1, 128), 0);
    int above = min(inds, 128);
    float c0 = s_cdf[wv][below], c1 = s_cdf[wv][above];
    float b0 = (float)below * (1.0f / 128.0f);
    float b1 = (float)above * (1.0f / 128.0f);
    float t = (u - c0) / (c1 - c0);
    t = fminf(fmaxf(t, 0.0f), 1.0f);  // NaN->0 (IEEE maxNum), +inf->1: matches nan_to_num+clip
    float bvv = b0 + t * (b1 - b0);
    s_bins1[wv][j] = bvv;
    s_rb1[wv][j] = spacing_inv_fn(s_near * (1.0f - bvv) + s_far * bvv);
  };
  sample_one(lane);
  if (lane == 63) sample_one(64);
  __syncthreads();

  // ---- fine level: lane owns sample t=lane
  const float rbl = s_rb1[wv][lane];
  const float rbl1 = s_rb1[wv][lane + 1];
  const float delta = rbl1 - rbl;
  const float sgf = sig_f[ray * 64 + lane];
  const float dsf = delta * sgf;
  const float Sf = scan_incl(dsf, lane);
  float w1 = (1.0f - expf(-dsf)) * expf(-(Sf - dsf));
  if (w1 != w1) w1 = 0.0f;
  const float tmid = 0.5f * (rbl + rbl1);

  // xyz + MERF contraction
  float px = ro[0] + rd[0] * tmid;
  float py = ro[1] + rd[1] * tmid;
  float pz = ro[2] + rd[2] * tmid;
  float cx = px, cy = py, cz = pz;
  {
    float ax = fabsf(px), ay = fabsf(py), az = fabsf(pz);
    float mag = fmaxf(ax, fmaxf(ay, az));
    if (mag >= 1.0f) {
      float inv = 1.0f / mag;
      float so = (2.0f - inv) * inv;
      int idx = (ax >= ay && ax >= az) ? 0 : ((ay >= az) ? 1 : 2);
      cx = px * (idx == 0 ? so : inv);
      cy = py * (idx == 1 ? so : inv);
      cz = pz * (idx == 2 ? so : inv);
    }
  }

  const float wsum = wave_sum(w1);
  const float depth = wave_sum(w1 * tmid);
  const float fx = wave_sum(w1 * cx);
  const float fy = wave_sum(w1 * cy);
  const float fz = wave_sum(w1 * cz);

  s_w1[wv][lane] = w1;
  const float Scw = scan_incl(w1, lane);  // inclusive cumsum of w1
  s_cw1[wv][lane + 1] = Scw;
  if (lane == 0) s_cw1[wv][0] = 0.0f;

  // ---- distortion loss (per-lane, then wave reduce)
  const float bl = s_bins1[wv][lane];
  const float bl1 = s_bins1[wv][lane + 1];
  const float interval = bl1 - bl;
  const float mid = bl + interval * 0.5f;
  const float wm = w1 * mid;
  const float Swm = scan_incl(wm, lane);
  const float w_excl = Scw - w1;
  const float wm_excl = Swm - wm;
  const float dl = (1.0f / 3.0f) * (interval * w1 * w1) + 2.0f * (wm * w_excl - w1 * wm_excl);
  const float dist_part = wave_sum(dl);
  __syncthreads();

  // ---- interlevel (proposal) loss: lane handles i = 2l, 2l+1
  float prop_lane = 0.0f;
  {
    const float* b1p = &s_bins1[wv][0];
    const float* cwp = &s_cw1[wv][0];
#pragma unroll
    for (int k = 0; k < 2; ++k) {
      int i = 2 * lane + k;
      float w0v = (k == 0) ? w00 : w01;
      float vlo = (float)i * (1.0f / 128.0f);
      float vhi = (float)(i + 1) * (1.0f / 128.0f);
      int ilo = max(min(ss_right(b1p, 64, vlo) - 1, 63), 0);
      int ihi = min(ss_right(b1p + 1, 64, vhi), 63);
      float wint = cwp[ihi + 1] - cwp[ilo];
      float diff = fmaxf(w0v - wint, 0.0f);
      prop_lane += diff * diff / (w0v + 1e-8f);
    }
  }
  const float prop_part = wave_sum(prop_lane);

  // ---- color accumulation: lane = tg*4 + cg; fully coalesced 1KiB/wave float4 loads
  {
    const int tg = lane >> 2, cg = lane & 3;
    const float4* col4 = (const float4*)(colors + (size_t)ray * (T1N * CN));
    float a0 = 0.f, a1 = 0.f, a2 = 0.f, a3 = 0.f;
#pragma unroll
    for (int it = 0; it < 4; ++it) {
      int t = tg + 16 * it;
      float wvv = s_w1[wv][t];
      float4 cvv = col4[t * 4 + cg];
      a0 = fmaf(wvv, cvv.x, a0);
      a1 = fmaf(wvv, cvv.y, a1);
      a2 = fmaf(wvv, cvv.z, a2);
      a3 = fmaf(wvv, cvv.w, a3);
    }
#pragma unroll
    for (int m = 4; m < 64; m <<= 1) {  // reduce over tg bits
      a0 += __shfl_xor(a0, m, 64);
      a1 += __shfl_xor(a1, m, 64);
      a2 += __shfl_xor(a2, m, 64);
      a3 += __shfl_xor(a3, m, 64);
    }
    if (lane < 4) {
      s_fimg[wv][lane * 4 + 0] = a0;
      s_fimg[wv][lane * 4 + 1] = a1;
      s_fimg[wv][lane * 4 + 2] = a2;
      s_fimg[wv][lane * 4 + 3] = a3;
    }
  }
  __syncthreads();

  // ---- epilogue: image = sigmoid(f_image @ w_view + b_view) + (1 - wsum)
  if (lane < 3) {
    float acc = b_view[lane];
#pragma unroll
    for (int c = 0; c < 16; ++c) acc = fmaf(s_fimg[wv][c], w_view[c * 3 + lane], acc);
    out[IMG_OFF + ray * 3 + lane] = 1.0f / (1.0f + expf(-acc)) + (1.0f - wsum);
    out[FXYZ_OFF + ray * 3 + lane] = (lane == 0) ? fx : ((lane == 1) ? fy : fz);
  }
  if (lane == 0) {
    out[DEPTH_OFF + ray] = depth;
    s_scal[wv][0] = prop_part;
    s_scal[wv][1] = dist_part;
  }
  __syncthreads();
  if (threadIdx.x == 0) {
    float P = s_scal[0][0] + s_scal[1][0] + s_scal[2][0] + s_scal[3][0];
    float D = s_scal[0][1] + s_scal[1][1] + s_scal[2][1] + s_scal[3][1];
    if (use_atomic) {
      atomicAdd(out + PROP_OFF, P * (1.0f / ((float)NRAYS * 128.0f)));
      atomicAdd(out + DIST_OFF, D * (1.0f / (float)NRAYS));
    } else {
      ws_partials[blockIdx.x] = P;
      ws_partials[NBLK + blockIdx.x] = D;
    }
  }
}

__global__ void __launch_bounds__(256) reduce_partials(const float* __restrict__ ws,
                                                       float* __restrict__ out) {
  float p = 0.0f, d = 0.0f;
  for (int i = threadIdx.x; i < NBLK; i += 256) {
    p += ws[i];
    d += ws[NBLK + i];
  }
  p = wave_sum(p);
  d = wave_sum(d);
  __shared__ float sp[4], sd[4];
  const int wv = threadIdx.x >> 6, lane = threadIdx.x & 63;
  if (lane == 0) { sp[wv] = p; sd[wv] = d; }
  __syncthreads();
  if (threadIdx.x == 0) {
    float P = sp[0] + sp[1] + sp[2] + sp[3];
    float D = sd[0] + sd[1] + sd[2] + sd[3];
    out[PROP_OFF] = P * (1.0f / ((float)NRAYS * 128.0f));
    out[DIST_OFF] = D * (1.0f / (float)NRAYS);
  }
}

extern "C" void kernel_launch(void* const* d_in, const int* in_sizes, int n_in,
                              void* d_out, int out_size, void* d_ws, size_t ws_size,
                              hipStream_t stream) {
  const float* rays_o = (const float*)d_in[0];
  const float* rays_d = (const float*)d_in[1];
  const float* aabb = (const float*)d_in[2];
  const float* sig_c = (const float*)d_in[3];
  const float* sig_f = (const float*)d_in[4];
  const float* colors = (const float*)d_in[5];
  const float* w_view = (const float*)d_in[6];
  const float* b_view = (const float*)d_in[7];
  float* out = (float*)d_out;
  float* wsf = (float*)d_ws;

  const bool use_ws = (ws_size >= (size_t)(2 * NBLK) * sizeof(float)) && (wsf != nullptr);
  if (!use_ws) {
    // atomic fallback path: zero the two scalar-loss slots first
    hipMemsetAsync(out + PROP_OFF, 0, 2 * sizeof(float), stream);
  }
  nerf_main<<<NBLK, 256, 0, stream>>>(rays_o, rays_d, aabb, sig_c, sig_f, colors,
                                      w_view, b_view, out, wsf, use_ws ? 0 : 1);
  if (use_ws) reduce_partials<<<1, 256, 0, stream>>>(wsf, out);
}

// Round 2
// 410.671 us; speedup vs baseline: 1.0703x; 1.0703x over previous
//
#include <hip/hip_runtime.h>
#include <math.h>

#define NRAYS 65536
#define T0N 128
#define T1N 64
#define CN 16
#define RPB 4                   // rays (waves) per block
#define NBLK (NRAYS / RPB)      // 16384

#define IMG_OFF   0
#define DEPTH_OFF (NRAYS * 3)
#define FXYZ_OFF  (NRAYS * 4)
#define PROP_OFF  (NRAYS * 7)
#define DIST_OFF  (NRAYS * 7 + 1)

__device__ __forceinline__ float wave_sum(float x) {
#pragma unroll
  for (int off = 1; off < 64; off <<= 1) x += __shfl_xor(x, off, 64);
  return x;  // all lanes hold the total
}

__device__ __forceinline__ float scan_incl(float x, int lane) {
#pragma unroll
  for (int off = 1; off < 64; off <<= 1) {
    float y = __shfl_up(x, off, 64);
    if (lane >= off) x += y;
  }
  return x;  // inclusive prefix sum across 64 lanes
}

// Wave-internal LDS producer->consumer sync. All our LDS arrays are indexed
// by [wv] (wave-private), so no cross-wave barrier is needed; this waits
// lgkmcnt only and does NOT drain vmcnt like __syncthreads would — the
// prefetched colors loads stay in flight.
__device__ __forceinline__ void wave_lds_sync() {
  __builtin_amdgcn_wave_barrier();
  __builtin_amdgcn_fence(__ATOMIC_ACQ_REL, "workgroup");
  __builtin_amdgcn_wave_barrier();
}

__device__ __forceinline__ float spacing_fn(float x) {
  return (x < 1.0f) ? (x * 0.5f) : (1.0f - 1.0f / (2.0f * x));
}
__device__ __forceinline__ float spacing_inv_fn(float x) {
  return (x < 0.5f) ? (2.0f * x) : (1.0f / (2.0f - 2.0f * x));
}

// searchsorted side='right': count of a[m] <= v
__device__ __forceinline__ int ss_right(const float* a, int n, float v) {
  int lo = 0, hi = n;
  while (lo < hi) {
    int m = (lo + hi) >> 1;
    if (a[m] <= v) lo = m + 1; else hi = m;
  }
  return lo;
}

__global__ void __launch_bounds__(256) nerf_main(
    const float* __restrict__ rays_o, const float* __restrict__ rays_d,
    const float* __restrict__ aabb, const float* __restrict__ sig_c,
    const float* __restrict__ sig_f, const float* __restrict__ colors,
    const float* __restrict__ w_view, const float* __restrict__ b_view,
    float* __restrict__ out, float* __restrict__ ws_partials, int use_atomic) {
  __shared__ float s_cdf[RPB][130];
  __shared__ float s_bins1[RPB][65];
  __shared__ float s_cw1[RPB][65];
  __shared__ float s_scal[RPB][2];

  const int wv = threadIdx.x >> 6;
  const int lane = threadIdx.x & 63;
  const int ray = blockIdx.x * RPB + wv;

  // ---- prefetch: colors (4 KiB/ray, 1 KiB/wave-instr, fully coalesced) and
  // sigmas issue NOW; consumed only at the end / after the coarse phase.
  const int tg = lane >> 2, cg = lane & 3;
  const float4* col4 = (const float4*)(colors + (size_t)ray * (T1N * CN));
  const float4 cva = col4[(tg + 0) * 4 + cg];
  const float4 cvb = col4[(tg + 16) * 4 + cg];
  const float4 cvc = col4[(tg + 32) * 4 + cg];
  const float4 cvd = col4[(tg + 48) * 4 + cg];
  const float2 sg = ((const float2*)sig_c)[ray * 64 + lane];
  const float sgf = sig_f[ray * 64 + lane];

  // ---- ray setup: near/far from aabb
  float ro[3], rd[3];
#pragma unroll
  for (int c = 0; c < 3; ++c) { ro[c] = rays_o[ray * 3 + c]; rd[c] = rays_d[ray * 3 + c]; }
  float near = -3.0e38f, far = 3.0e38f;
#pragma unroll
  for (int c = 0; c < 3; ++c) {
    float dd = rd[c] + 1e-15f;
    float ta = (aabb[c] - ro[c]) / dd;
    float tb = (aabb[c + 3] - ro[c]) / dd;
    near = fmaxf(near, fminf(ta, tb));
    far = fminf(far, fmaxf(ta, tb));
  }
  if (far < near) { near = 1e9f; far = 1e9f; }
  near = fmaxf(near, 0.05f);
  const float s_near = spacing_fn(near), s_far = spacing_fn(far);

  // ---- coarse level: lane owns bins0 samples 2l, 2l+1
  const int i0 = 2 * lane, i1 = 2 * lane + 1;
  const float b_a = (float)i0 * (1.0f / 128.0f);
  const float b_b = (float)i1 * (1.0f / 128.0f);
  const float b_c = (float)(i1 + 1) * (1.0f / 128.0f);
  const float rb_a = spacing_inv_fn(s_near * (1.0f - b_a) + s_far * b_a);
  const float rb_b = spacing_inv_fn(s_near * (1.0f - b_b) + s_far * b_b);
  const float rb_c = spacing_inv_fn(s_near * (1.0f - b_c) + s_far * b_c);
  const float ds0 = (rb_b - rb_a) * sg.x;
  const float ds1 = (rb_c - rb_b) * sg.y;
  const float pr = ds0 + ds1;
  const float Spr = scan_incl(pr, lane);
  const float E0 = Spr - pr;            // exclusive cumsum of ds at 2l
  const float e0 = __expf(-E0);
  const float ed0 = __expf(-ds0);
  float w00 = (1.0f - ed0) * e0;
  float w01 = (1.0f - __expf(-ds1)) * (e0 * ed0);
  if (w00 != w00) w00 = 0.0f;  // nan_to_num
  if (w01 != w01) w01 = 0.0f;

  // ---- pdf/cdf: one scan; total comes from lane 63 (no extra wave_sum)
  const float wp0 = w00 + 0.01f, wp1 = w01 + 0.01f;
  const float S2 = scan_incl(wp0 + wp1, lane);   // inclusive cumsum of wp
  const float tot = __shfl(S2, 63, 64);
  const float rt = 1.0f / tot;
  s_cdf[wv][i0 + 1] = fminf((S2 - wp1) * rt, 1.0f);
  s_cdf[wv][i1 + 1] = fminf(S2 * rt, 1.0f);
  if (lane == 0) s_cdf[wv][0] = 0.0f;
  wave_lds_sync();

  // ---- inverse-CDF sampling of 65 new bins (lane j; lane 63 also j=64)
  auto sample_one = [&](int j) -> float {
    const float u = ((float)j + 0.5f) * (1.0f / 65.0f);
    int inds = ss_right(&s_cdf[wv][0], 129, u);
    int below = max(min(inds - 1, 128), 0);
    int above = min(inds, 128);
    float c0 = s_cdf[wv][below], c1 = s_cdf[wv][above];
    float b0 = (float)below * (1.0f / 128.0f);
    float b1 = (float)above * (1.0f / 128.0f);
    float t = (u - c0) / (c1 - c0);
    t = fminf(fmaxf(t, 0.0f), 1.0f);  // NaN->0, +inf->1 == nan_to_num+clip
    float bvv = b0 + t * (b1 - b0);
    s_bins1[wv][j] = bvv;
    return bvv;
  };
  const float bv = sample_one(lane);
  float bv64 = 0.0f;
  if (lane == 63) bv64 = sample_one(64);
  float bvn = __shfl_down(bv, 1, 64);   // bins1[lane+1]
  if (lane == 63) bvn = bv64;

  // ---- fine level: lane owns sample t=lane (rb1 via registers, no LDS)
  const float rbl  = spacing_inv_fn(s_near * (1.0f - bv)  + s_far * bv);
  const float rbl1 = spacing_inv_fn(s_near * (1.0f - bvn) + s_far * bvn);
  const float dsf = (rbl1 - rbl) * sgf;
  const float Sf = scan_incl(dsf, lane);
  float w1 = (1.0f - __expf(-dsf)) * __expf(-(Sf - dsf));
  if (w1 != w1) w1 = 0.0f;
  const float tmid = 0.5f * (rbl + rbl1);

  // xyz + MERF contraction
  float px = ro[0] + rd[0] * tmid;
  float py = ro[1] + rd[1] * tmid;
  float pz = ro[2] + rd[2] * tmid;
  float cx = px, cy = py, cz = pz;
  {
    float ax = fabsf(px), ay = fabsf(py), az = fabsf(pz);
    float mag = fmaxf(ax, fmaxf(ay, az));
    if (mag >= 1.0f) {
      float inv = 1.0f / mag;
      float so = (2.0f - inv) * inv;
      int idx = (ax >= ay && ax >= az) ? 0 : ((ay >= az) ? 1 : 2);
      cx = px * (idx == 0 ? so : inv);
      cy = py * (idx == 1 ? so : inv);
      cz = pz * (idx == 2 ? so : inv);
    }
  }

  const float Scw = scan_incl(w1, lane);    // inclusive cumsum of w1
  const float wsum = __shfl(Scw, 63, 64);   // total from lane 63
  const float depth = wave_sum(w1 * tmid);
  const float fx = wave_sum(w1 * cx);
  const float fy = wave_sum(w1 * cy);
  const float fz = wave_sum(w1 * cz);
  s_cw1[wv][lane + 1] = Scw;
  if (lane == 0) s_cw1[wv][0] = 0.0f;

  // ---- distortion loss (bins1 values live in regs)
  const float interval = bvn - bv;
  const float mid = bv + interval * 0.5f;
  const float wm = w1 * mid;
  const float Swm = scan_incl(wm, lane);
  const float dl = (1.0f / 3.0f) * (interval * w1 * w1) +
                   2.0f * (wm * (Scw - w1) - w1 * (Swm - wm));
  const float dist_part = wave_sum(dl);
  wave_lds_sync();  // covers s_bins1 + s_cw1 before interlevel reads

  // ---- interlevel (proposal) loss: lane handles i = 2l, 2l+1
  float prop_lane = 0.0f;
  {
    const float* b1p = &s_bins1[wv][0];
    const float* cwp = &s_cw1[wv][0];
#pragma unroll
    for (int k = 0; k < 2; ++k) {
      int i = 2 * lane + k;
      float w0v = (k == 0) ? w00 : w01;
      float vlo = (float)i * (1.0f / 128.0f);
      float vhi = (float)(i + 1) * (1.0f / 128.0f);
      int ilo = max(min(ss_right(b1p, 64, vlo) - 1, 63), 0);
      int ihi = min(ss_right(b1p + 1, 64, vhi), 63);
      float wint = cwp[ihi + 1] - cwp[ilo];
      float diff = fmaxf(w0v - wint, 0.0f);
      prop_lane += diff * diff / (w0v + 1e-8f);
    }
  }
  const float prop_part = wave_sum(prop_lane);

  // ---- color accumulation: consume prefetched registers; weights via shfl
  float a0, a1, a2, a3;
  {
    const float wv0 = __shfl(w1, tg, 64);
    const float wv1 = __shfl(w1, tg + 16, 64);
    const float wv2 = __shfl(w1, tg + 32, 64);
    const float wv3 = __shfl(w1, tg + 48, 64);
    a0 = fmaf(wv0, cva.x, fmaf(wv1, cvb.x, fmaf(wv2, cvc.x, wv3 * cvd.x)));
    a1 = fmaf(wv0, cva.y, fmaf(wv1, cvb.y, fmaf(wv2, cvc.y, wv3 * cvd.y)));
    a2 = fmaf(wv0, cva.z, fmaf(wv1, cvb.z, fmaf(wv2, cvc.z, wv3 * cvd.z)));
    a3 = fmaf(wv0, cva.w, fmaf(wv1, cvb.w, fmaf(wv2, cvc.w, wv3 * cvd.w)));
#pragma unroll
    for (int m = 4; m < 64; m <<= 1) {  // reduce over tg bits
      a0 += __shfl_xor(a0, m, 64);
      a1 += __shfl_xor(a1, m, 64);
      a2 += __shfl_xor(a2, m, 64);
      a3 += __shfl_xor(a3, m, 64);
    }
  }
  // a0..a3 now hold f_image[4cg..4cg+3]; finish matvec in-register
  float acc0 = 0.f, acc1 = 0.f, acc2 = 0.f;
  {
    const int ch = cg * 4;
    const float* wvp = w_view + ch * 3;
    acc0 = fmaf(a0, wvp[0], fmaf(a1, wvp[3], fmaf(a2, wvp[6], a3 * wvp[9])));
    acc1 = fmaf(a0, wvp[1], fmaf(a1, wvp[4], fmaf(a2, wvp[7], a3 * wvp[10])));
    acc2 = fmaf(a0, wvp[2], fmaf(a1, wvp[5], fmaf(a2, wvp[8], a3 * wvp[11])));
#pragma unroll
    for (int m = 1; m < 4; m <<= 1) {  // reduce over cg bits
      acc0 += __shfl_xor(acc0, m, 64);
      acc1 += __shfl_xor(acc1, m, 64);
      acc2 += __shfl_xor(acc2, m, 64);
    }
  }

  // ---- epilogue
  if (lane < 3) {
    float acc = (lane == 0) ? acc0 : ((lane == 1) ? acc1 : acc2);
    acc += b_view[lane];
    out[IMG_OFF + ray * 3 + lane] = 1.0f / (1.0f + __expf(-acc)) + (1.0f - wsum);
    out[FXYZ_OFF + ray * 3 + lane] = (lane == 0) ? fx : ((lane == 1) ? fy : fz);
  }
  if (lane == 0) {
    out[DEPTH_OFF + ray] = depth;
    s_scal[wv][0] = prop_part;
    s_scal[wv][1] = dist_part;
  }
  __syncthreads();  // only cross-wave communication in the kernel
  if (threadIdx.x == 0) {
    float P = s_scal[0][0] + s_scal[1][0] + s_scal[2][0] + s_scal[3][0];
    float D = s_scal[0][1] + s_scal[1][1] + s_scal[2][1] + s_scal[3][1];
    if (use_atomic) {
      atomicAdd(out + PROP_OFF, P * (1.0f / ((float)NRAYS * 128.0f)));
      atomicAdd(out + DIST_OFF, D * (1.0f / (float)NRAYS));
    } else {
      ws_partials[blockIdx.x] = P;
      ws_partials[NBLK + blockIdx.x] = D;
    }
  }
}

__global__ void __launch_bounds__(256) reduce_partials(const float* __restrict__ ws,
                                                       float* __restrict__ out) {
  const float4* w4 = (const float4*)ws;
  float p = 0.0f, d = 0.0f;
  for (int i = threadIdx.x; i < NBLK / 4; i += 256) {
    float4 a = w4[i];
    p += (a.x + a.y) + (a.z + a.w);
    float4 b = w4[NBLK / 4 + i];
    d += (b.x + b.y) + (b.z + b.w);
  }
  p = wave_sum(p);
  d = wave_sum(d);
  __shared__ float sp[4], sd[4];
  const int wv = threadIdx.x >> 6, lane = threadIdx.x & 63;
  if (lane == 0) { sp[wv] = p; sd[wv] = d; }
  __syncthreads();
  if (threadIdx.x == 0) {
    float P = sp[0] + sp[1] + sp[2] + sp[3];
    float D = sd[0] + sd[1] + sd[2] + sd[3];
    out[PROP_OFF] = P * (1.0f / ((float)NRAYS * 128.0f));
    out[DIST_OFF] = D * (1.0f / (float)NRAYS);
  }
}

extern "C" void kernel_launch(void* const* d_in, const int* in_sizes, int n_in,
                              void* d_out, int out_size, void* d_ws, size_t ws_size,
                              hipStream_t stream) {
  const float* rays_o = (const float*)d_in[0];
  const float* rays_d = (const float*)d_in[1];
  const float* aabb = (const float*)d_in[2];
  const float* sig_c = (const float*)d_in[3];
  const float* sig_f = (const float*)d_in[4];
  const float* colors = (const float*)d_in[5];
  const float* w_view = (const float*)d_in[6];
  const float* b_view = (const float*)d_in[7];
  float* out = (float*)d_out;
  float* wsf = (float*)d_ws;

  const bool use_ws = (ws_size >= (size_t)(2 * NBLK) * sizeof(float)) && (wsf != nullptr);
  if (!use_ws) {
    hipMemsetAsync(out + PROP_OFF, 0, 2 * sizeof(float), stream);
  }
  nerf_main<<<NBLK, 256, 0, stream>>>(rays_o, rays_d, aabb, sig_c, sig_f, colors,
                                      w_view, b_view, out, wsf, use_ws ? 0 : 1);
  if (use_ws) reduce_partials<<<1, 256, 0, stream>>>(wsf, out);
}